// Round 7
// baseline (1881.053 us; speedup 1.0000x reference)
//
#include <hip/hip_runtime.h>
#include <math.h>
#include <stdint.h>

#define Bb 64
#define Nn 4096
#define Uu 64
#define RL 4224                         // 64*66
#define NU (Nn*Uu)
#define MATSZ ((size_t)Nn*(size_t)RL)   // elements per feature matrix
#define ELLW 112                        // ELL row capacity (avg nnz ~42)
#define XSTR 360                        // K-stride (bf16) in gemm LDS, pad of 352

typedef __attribute__((ext_vector_type(8))) short short8;
typedef __attribute__((ext_vector_type(4))) float f32x4;
typedef unsigned int uint;
typedef unsigned short ushort;

__device__ inline uint f2bf(float f){ uint u=__float_as_uint(f); u += 0x7fffu + ((u>>16)&1u); return u>>16; }
__device__ inline uint pack2(float a,float b){
  uint ua=__float_as_uint(a); ua+=0x7fffu+((ua>>16)&1u);
  uint ub=__float_as_uint(b); ub+=0x7fffu+((ub>>16)&1u);
  return (ua>>16)|(ub&0xffff0000u);
}
__device__ inline float blo(uint u){ return __uint_as_float(u << 16); }
__device__ inline float bhi(uint u){ return __uint_as_float(u & 0xffff0000u); }

// ---------------- ELL extraction: one pass, no scan ----------------
// pkv[row*112 + i] = (bf16(val)<<16) | col ; rcnt[row] = count rounded up to 4 (zero-padded)
__global__ __launch_bounds__(256) void k_fill(const float* __restrict__ sup,
                                              uint* __restrict__ pkv, int* __restrict__ rcnt) {
  const int lane = threadIdx.x & 63;
  const int row = blockIdx.x * 4 + (threadIdx.x >> 6);
  const float* rp = sup + (size_t)row * Nn;
  uint* outp = pkv + (size_t)row * ELLW;
  const unsigned long long lt = (1ull << lane) - 1ull;
  int off = 0;
  for (int j0 = 0; j0 < Nn; j0 += 64) {
    float v = rp[j0 + lane];
    unsigned long long m = __ballot(v != 0.0f);
    if (v != 0.0f) {
      int pos = off + (int)__popcll(m & lt);
      if (pos < ELLW) outp[pos] = (f2bf(v) << 16) | (uint)(j0 + lane);
    }
    off += (int)__popcll(m);
  }
  if (off > ELLW) off = ELLW;
  const int c4 = (off + 3) & ~3;
  if (lane < c4 - off) outp[off + lane] = 0u;    // zero pad: contributes nothing
  if (lane == 0) rcnt[row] = c4;
}

// ---------------- x0 = [inputs | hx] bf16 in [n][b][f], vectorized ----------------
__global__ __launch_bounds__(256) void k_bx0(const float* __restrict__ inp, const float* __restrict__ hx,
                                             ushort* __restrict__ x0) {
  const int n = blockIdx.x;
  const int b = threadIdx.x >> 2, q = threadIdx.x & 3;
  const float* hp = hx + (size_t)b*NU + (size_t)n*Uu + q*16;
  ushort* xp = x0 + (size_t)n*RL + b*66;
  #pragma unroll
  for (int i = 0; i < 4; ++i) {
    const float4 v = *(const float4*)&hp[i*4];
    const int o = 2 + q*16 + i*4;
    *(uint*)&xp[o]     = pack2(v.x, v.y);
    *(uint*)&xp[o + 2] = pack2(v.z, v.w);
  }
  if (q == 0) {
    const float2 iv = *(const float2*)&inp[(size_t)b*(size_t)(Nn*2) + (size_t)n*2];
    *(uint*)&xp[0] = pack2(iv.x, iv.y);
  }
}

// ---------------- 4-nnz batch: 4 ds_read_b64 + FMAs ----------------
#define PROC4(E)                                                                              \
  {                                                                                           \
    const uint A0 = (E.x << 4) & 0xffff0u; const uint2 w0 = *(const uint2*)(slb + A0 + cg8);  \
    const uint A1 = (E.y << 4) & 0xffff0u; const uint2 w1 = *(const uint2*)(slb + A1 + cg8);  \
    const uint A2 = (E.z << 4) & 0xffff0u; const uint2 w2 = *(const uint2*)(slb + A2 + cg8);  \
    const uint A3 = (E.w << 4) & 0xffff0u; const uint2 w3 = *(const uint2*)(slb + A3 + cg8);  \
    const float b0 = bhi(E.x), b1 = bhi(E.y), b2 = bhi(E.z), b3 = bhi(E.w);                   \
    a0 += b0*blo(w0.x); a1 += b0*bhi(w0.x); a2 += b0*blo(w0.y); a3 += b0*bhi(w0.y);           \
    a0 += b1*blo(w1.x); a1 += b1*bhi(w1.x); a2 += b1*blo(w1.y); a3 += b1*bhi(w1.y);           \
    a0 += b2*blo(w2.x); a1 += b2*bhi(w2.x); a2 += b2*blo(w2.y); a3 += b2*bhi(w2.y);           \
    a0 += b3*blo(w3.x); a1 += b3*bhi(w3.x); a2 += b3*blo(w3.y); a3 += b3*bhi(w3.y);           \
  }

// ---------------- fused gconv SpMM: y1_s = A_s@x ; y2_s = 2*A_s@y1_s - x ----------------
// One block owns one 8-col slice (unit) for ALL rows -> y1 for its columns is entirely
// block-local: stage x once (64KB slab, 2 blocks/CU, 8 waves/SIMD), walk1 for both
// supports from the shared slab, write y1, then per support restage y1 (L2-hot, same
// XCD) and walk2 with the Chebyshev combine + x re-read. Natural row order: coalesced
// stores, sequential ELL streams. Grid 528 = 66 units x 8 XCDs, no tail tasks.
__global__ __launch_bounds__(1024, 8) void k_gconv(const ushort* __restrict__ x0,
                                                   ushort* __restrict__ y1, ushort* __restrict__ y2,
                                                   const int* __restrict__ rcnt,
                                                   const uint* __restrict__ pkv) {
  __shared__ ushort slab[4096*8];                        // 64 KiB, rows 16B
  const char* slb = (const char*)slab;
  const int t = threadIdx.x, cg = t & 1, rh = t >> 1;    // 2 lanes per row
  const int cg8 = cg * 8;
  const int unit = (blockIdx.x & 7)*66 + (blockIdx.x >> 3);
  const int c0 = unit * 8;
  // stage x slab
  #pragma unroll
  for (int it = 0; it < 4; ++it) {
    const int j = it*1024 + t;
    *(uint4*)&slab[j*8] = *(const uint4*)&x0[(size_t)j*RL + c0];
  }
  __syncthreads();
  // walk1: both supports read the shared x slab
  for (int s = 0; s < 2; ++s) {
    ushort* yo = y1 + (size_t)s*MATSZ + c0;
    const int sb = s << 12;
    for (int it = 0; it < 8; ++it) {
      const int row = it*512 + rh;
      int p = (sb + row)*ELLW;
      const int pe = p + rcnt[sb + row];
      float a0=0.f, a1=0.f, a2=0.f, a3=0.f;
      uint4 e = *(const uint4*)&pkv[p]; p += 4;
      for (; p < pe; p += 4) { const uint4 en = *(const uint4*)&pkv[p]; PROC4(e); e = en; }
      PROC4(e);
      uint2 o; o.x = pack2(a0, a1); o.y = pack2(a2, a3);
      *(uint2*)&yo[(size_t)row*RL + cg*4] = o;
    }
  }
  __threadfence_block();                                 // y1 writes visible to block
  // walk2 per support: restage y1_s (block-local, L2-hot), Chebyshev combine
  for (int s = 0; s < 2; ++s) {
    __syncthreads();                                     // walkers done before overwrite
    const ushort* ys = y1 + (size_t)s*MATSZ + c0;
    #pragma unroll
    for (int it = 0; it < 4; ++it) {
      const int j = it*1024 + t;
      *(uint4*)&slab[j*8] = *(const uint4*)&ys[(size_t)j*RL];
    }
    __syncthreads();
    ushort* yo = y2 + (size_t)s*MATSZ + c0;
    const int sb = s << 12;
    for (int it = 0; it < 8; ++it) {
      const int row = it*512 + rh;
      int p = (sb + row)*ELLW;
      const int pe = p + rcnt[sb + row];
      float a0=0.f, a1=0.f, a2=0.f, a3=0.f;
      uint4 e = *(const uint4*)&pkv[p]; p += 4;
      for (; p < pe; p += 4) { const uint4 en = *(const uint4*)&pkv[p]; PROC4(e); e = en; }
      PROC4(e);
      const uint2 xv = *(const uint2*)&x0[(size_t)row*RL + c0 + cg*4];
      uint2 o;
      o.x = pack2(2.f*a0 - blo(xv.x), 2.f*a1 - bhi(xv.x));
      o.y = pack2(2.f*a2 - blo(xv.y), 2.f*a3 - bhi(xv.y));
      *(uint2*)&yo[(size_t)row*RL + cg*4] = o;
    }
  }
}

// ---------------- W pre-pack into MFMA B-fragment order (bf16) ----------------
__global__ __launch_bounds__(256) void k_wpack(const float* __restrict__ W1, const float* __restrict__ W2,
                                               ushort* __restrict__ Wp1, ushort* __restrict__ Wp2) {
  const int tid = blockIdx.x*256 + threadIdx.x;
  const int i = tid & 7, l = (tid >> 3) & 63;
  if (tid < 45056) {
    const int g = tid >> 9, tt = g / 11, kk = g % 11;
    const int r = kk*32 + (l>>4)*8 + i, c = tt*16 + (l & 15);
    Wp1[tid] = (r < 330) ? (ushort)f2bf(W1[(size_t)r*128 + c]) : (ushort)0;
  } else {
    const int t2 = tid - 45056;
    const int g = t2 >> 9, tt = g / 11, kk = g % 11;
    const int r = kk*32 + (l>>4)*8 + i, c = tt*16 + (l & 15);
    Wp2[t2] = (r < 330) ? (ushort)f2bf(W2[(size_t)r*64 + c]) : (ushort)0;
  }
}

// ---------------- gconv1 output GEMM (MFMA), fused sigmoid + r*hx + u ----------------
__global__ __launch_bounds__(256) void k_gemm1(const ushort* __restrict__ x0, const ushort* __restrict__ y1,
                                               const ushort* __restrict__ y2, const ushort* __restrict__ Wp,
                                               const float* __restrict__ bias, const float* __restrict__ hx,
                                               ushort* __restrict__ x0w, ushort* __restrict__ ubuf) {
  __shared__ ushort Xs[64*XSTR];
  const int n = blockIdx.x, t = threadIdx.x;
  for (int q = t; q < 64*XSTR/4; q += 256) ((unsigned long long*)Xs)[q] = 0ull;
  __syncthreads();
  for (int m = 0; m < 5; ++m) {
    const ushort* mp;
    if (m == 0) mp = x0; else { mp = (m & 1) ? y1 : y2; if (m >= 3) mp += MATSZ; }
    mp += (size_t)n * RL;
    for (int q = t; q < RL; q += 256) {
      const int b = q / 66, f = q - b*66;
      Xs[b*XSTR + f*5 + m] = mp[q];
    }
  }
  __syncthreads();
  const int w = t >> 6, l = t & 63;
  const int b0 = w * 16;
  f32x4 acc[8];
  for (int i = 0; i < 8; ++i) acc[i] = (f32x4){0.f,0.f,0.f,0.f};
  const int arow = b0 + (l & 15), koff0 = (l >> 4) * 8;
  for (int kk = 0; kk < 11; ++kk) {
    const short8 af = *(const short8*)&Xs[arow*XSTR + kk*32 + koff0];
    #pragma unroll
    for (int tt = 0; tt < 8; ++tt) {
      const short8 bf = *(const short8*)&Wp[(((size_t)tt*11 + kk)*64 + l)*8];
      acc[tt] = __builtin_amdgcn_mfma_f32_16x16x32_bf16(af, bf, acc[tt], 0, 0, 0);
    }
  }
  const int rg = (l >> 4) * 4;
  #pragma unroll
  for (int tt = 0; tt < 8; ++tt) {
    const int o = tt*16 + (l & 15);
    const float bs = bias[o];
    #pragma unroll
    for (int r = 0; r < 4; ++r) {
      const int b = b0 + rg + r;
      const float v = acc[tt][r] + bs;
      const float sg = 1.0f / (1.0f + __expf(-v));
      if (o < Uu) {
        const float h = hx[(size_t)b*NU + (size_t)n*Uu + o];
        x0w[(size_t)n*RL + b*66 + 2 + o] = (ushort)f2bf(sg * h);
      } else {
        ubuf[(size_t)b*NU + (size_t)n*Uu + (o - Uu)] = (ushort)f2bf(sg);
      }
    }
  }
}

// ---------------- gconv2 output GEMM (MFMA), fused tanh + final gate ----------------
__global__ __launch_bounds__(256) void k_gemm2(const ushort* __restrict__ x0, const ushort* __restrict__ y1,
                                               const ushort* __restrict__ y2, const ushort* __restrict__ Wp,
                                               const float* __restrict__ bias, const float* __restrict__ hx,
                                               const ushort* __restrict__ ubuf, float* __restrict__ out) {
  __shared__ ushort Xs[64*XSTR];
  const int n = blockIdx.x, t = threadIdx.x;
  for (int q = t; q < 64*XSTR/4; q += 256) ((unsigned long long*)Xs)[q] = 0ull;
  __syncthreads();
  for (int m = 0; m < 5; ++m) {
    const ushort* mp;
    if (m == 0) mp = x0; else { mp = (m & 1) ? y1 : y2; if (m >= 3) mp += MATSZ; }
    mp += (size_t)n * RL;
    for (int q = t; q < RL; q += 256) {
      const int b = q / 66, f = q - b*66;
      Xs[b*XSTR + f*5 + m] = mp[q];
    }
  }
  __syncthreads();
  const int w = t >> 6, l = t & 63;
  const int b0 = w * 16;
  f32x4 acc[4];
  for (int i = 0; i < 4; ++i) acc[i] = (f32x4){0.f,0.f,0.f,0.f};
  const int arow = b0 + (l & 15), koff0 = (l >> 4) * 8;
  for (int kk = 0; kk < 11; ++kk) {
    const short8 af = *(const short8*)&Xs[arow*XSTR + kk*32 + koff0];
    #pragma unroll
    for (int tt = 0; tt < 4; ++tt) {
      const short8 bf = *(const short8*)&Wp[(((size_t)tt*11 + kk)*64 + l)*8];
      acc[tt] = __builtin_amdgcn_mfma_f32_16x16x32_bf16(af, bf, acc[tt], 0, 0, 0);
    }
  }
  const int rg = (l >> 4) * 4;
  #pragma unroll
  for (int tt = 0; tt < 4; ++tt) {
    const int o = tt*16 + (l & 15);
    const float bs = bias[o];
    #pragma unroll
    for (int r = 0; r < 4; ++r) {
      const int b = b0 + rg + r;
      const float c = tanhf(acc[tt][r] + bs);
      const size_t ix = (size_t)b*NU + (size_t)n*Uu + o;
      const float u = __uint_as_float(((uint)ubuf[ix]) << 16);
      const float h = hx[ix];
      out[ix] = u*h + (1.0f - u)*c;
    }
  }
}

extern "C" void kernel_launch(void* const* d_in, const int* in_sizes, int n_in,
                              void* d_out, int out_size, void* d_ws, size_t ws_size,
                              hipStream_t stream) {
  const float* inp = (const float*)d_in[0];
  const float* hx  = (const float*)d_in[1];
  const float* sup = (const float*)d_in[2];
  const float* ruW = (const float*)d_in[3];
  const float* ruB = (const float*)d_in[4];
  const float* gW  = (const float*)d_in[5];
  const float* gB  = (const float*)d_in[6];
  float* out = (float*)d_out;

  // workspace (bf16 intermediates): x0 | y1[2] | y2[2] | u | Wpk | ELL
  ushort* x0   = (ushort*)d_ws;
  ushort* y1   = x0 + MATSZ;
  ushort* y2   = y1 + 2*MATSZ;
  ushort* ubuf = y2 + 2*MATSZ;
  ushort* Wp1  = ubuf + (size_t)Bb*NU;
  ushort* Wp2  = Wp1 + 45056;
  uint* pkv  = (uint*)(Wp2 + 22528);          // 8192*112 uints, rows 16B-aligned
  int*  rcnt = (int*)(pkv + (size_t)8192*ELLW);

  k_fill<<<2048, 256, 0, stream>>>(sup, pkv, rcnt);
  k_wpack<<<264, 256, 0, stream>>>(ruW, gW, Wp1, Wp2);
  k_bx0<<<Nn, 256, 0, stream>>>(inp, hx, x0);

  // gconv1 (one fused SpMM dispatch: y1 = A@x0, y2 = 2A@y1 - x0, both supports)
  k_gconv<<<528, 1024, 0, stream>>>(x0, y1, y2, rcnt, pkv);
  k_gemm1<<<Nn, 256, 0, stream>>>(x0, y1, y2, Wp1, ruB, hx, x0, ubuf);
  // gconv2 (x0 state slots now hold bf16(r*hx))
  k_gconv<<<528, 1024, 0, stream>>>(x0, y1, y2, rcnt, pkv);
  k_gemm2<<<Nn, 256, 0, stream>>>(x0, y1, y2, Wp2, gB, hx, ubuf, out);
}

// Round 8
// 1014.474 us; speedup vs baseline: 1.8542x; 1.8542x over previous
//
#include <hip/hip_runtime.h>
#include <math.h>
#include <stdint.h>

#define Bb 64
#define Nn 4096
#define Uu 64
#define RL 4224                         // 64*66
#define NU (Nn*Uu)
#define MATSZ ((size_t)Nn*(size_t)RL)   // elements per feature matrix
#define ELLW 112                        // ELL row capacity (avg nnz ~42), multiple of 8
#define XSTR 360                        // K-stride (bf16) in gemm LDS, pad of 352

typedef __attribute__((ext_vector_type(8))) short short8;
typedef __attribute__((ext_vector_type(4))) float f32x4;
typedef unsigned int uint;
typedef unsigned short ushort;

__device__ inline uint f2bf(float f){ uint u=__float_as_uint(f); u += 0x7fffu + ((u>>16)&1u); return u>>16; }
__device__ inline uint pack2(float a,float b){
  uint ua=__float_as_uint(a); ua+=0x7fffu+((ua>>16)&1u);
  uint ub=__float_as_uint(b); ub+=0x7fffu+((ub>>16)&1u);
  return (ua>>16)|(ub&0xffff0000u);
}
__device__ inline float blo(uint u){ return __uint_as_float(u << 16); }
__device__ inline float bhi(uint u){ return __uint_as_float(u & 0xffff0000u); }

// ---------------- ELL extraction: one pass, counts padded to multiples of 8 ----------------
// pkv[row*112 + i] = (bf16(val)<<16) | col ; zero-pad entries contribute nothing
__global__ __launch_bounds__(256) void k_fill(const float* __restrict__ sup,
                                              uint* __restrict__ pkv, int* __restrict__ rcnt) {
  const int lane = threadIdx.x & 63;
  const int row = blockIdx.x * 4 + (threadIdx.x >> 6);
  const float* rp = sup + (size_t)row * Nn;
  uint* outp = pkv + (size_t)row * ELLW;
  const unsigned long long lt = (1ull << lane) - 1ull;
  int off = 0;
  for (int j0 = 0; j0 < Nn; j0 += 64) {
    float v = rp[j0 + lane];
    unsigned long long m = __ballot(v != 0.0f);
    if (v != 0.0f) {
      int pos = off + (int)__popcll(m & lt);
      if (pos < ELLW) outp[pos] = (f2bf(v) << 16) | (uint)(j0 + lane);
    }
    off += (int)__popcll(m);
  }
  if (off > ELLW) off = ELLW;
  const int c8 = (off + 7) & ~7;                 // <=112, 112%8==0
  if (lane < c8 - off) outp[off + lane] = 0u;
  if (lane == 0) rcnt[row] = c8;
}

// ---------------- x0 = [inputs | hx] bf16 in [n][b][f], vectorized ----------------
__global__ __launch_bounds__(256) void k_bx0(const float* __restrict__ inp, const float* __restrict__ hx,
                                             ushort* __restrict__ x0) {
  const int n = blockIdx.x;
  const int b = threadIdx.x >> 2, q = threadIdx.x & 3;
  const float* hp = hx + (size_t)b*NU + (size_t)n*Uu + q*16;
  ushort* xp = x0 + (size_t)n*RL + b*66;
  #pragma unroll
  for (int i = 0; i < 4; ++i) {
    const float4 v = *(const float4*)&hp[i*4];
    const int o = 2 + q*16 + i*4;
    *(uint*)&xp[o]     = pack2(v.x, v.y);
    *(uint*)&xp[o + 2] = pack2(v.z, v.w);
  }
  if (q == 0) {
    const float2 iv = *(const float2*)&inp[(size_t)b*(size_t)(Nn*2) + (size_t)n*2];
    *(uint*)&xp[0] = pack2(iv.x, iv.y);
  }
}

// ---------------- 4 nnz: 4 x ds_read_b128 (8 cols each) + FMAs ----------------
#define PROC4(E)                                                                      \
  {                                                                                   \
    const uint4 w0 = *(const uint4*)(slb + ((E.x << 4) & 0xffff0u));                  \
    const uint4 w1 = *(const uint4*)(slb + ((E.y << 4) & 0xffff0u));                  \
    const uint4 w2 = *(const uint4*)(slb + ((E.z << 4) & 0xffff0u));                  \
    const uint4 w3 = *(const uint4*)(slb + ((E.w << 4) & 0xffff0u));                  \
    const float b0 = bhi(E.x), b1 = bhi(E.y), b2 = bhi(E.z), b3 = bhi(E.w);           \
    a0 += b0*blo(w0.x); a1 += b0*bhi(w0.x); a2 += b0*blo(w0.y); a3 += b0*bhi(w0.y);   \
    a4 += b0*blo(w0.z); a5 += b0*bhi(w0.z); a6 += b0*blo(w0.w); a7 += b0*bhi(w0.w);   \
    a0 += b1*blo(w1.x); a1 += b1*bhi(w1.x); a2 += b1*blo(w1.y); a3 += b1*bhi(w1.y);   \
    a4 += b1*blo(w1.z); a5 += b1*bhi(w1.z); a6 += b1*blo(w1.w); a7 += b1*bhi(w1.w);   \
    a0 += b2*blo(w2.x); a1 += b2*bhi(w2.x); a2 += b2*blo(w2.y); a3 += b2*bhi(w2.y);   \
    a4 += b2*blo(w2.z); a5 += b2*bhi(w2.z); a6 += b2*blo(w2.w); a7 += b2*bhi(w2.w);   \
    a0 += b3*blo(w3.x); a1 += b3*bhi(w3.x); a2 += b3*blo(w3.y); a3 += b3*bhi(w3.y);   \
    a4 += b3*blo(w3.z); a5 += b3*bhi(w3.z); a6 += b3*blo(w3.w); a7 += b3*bhi(w3.w);   \
  }

// ---------------- SpMM: y = A@x (PASS2: y = 2*A@x - xsub) ----------------
// Slab = 4096 rows x 8 bf16 cols = 64 KiB -> 2 blocks/CU, 8 waves/SIMD. Natural row
// order: coalesced stores, sequential ELL streams (identical across blocks -> L2
// broadcast). 1 lane per row: ds_read_b128 serves all 8 cols. PASS1 stages x once and
// walks both supports. Schedule: 512 primary units (XCD-chunked: XCD x owns a
// contiguous 64-unit/512-col band) + 16 leftover units split 128-rows x 32 blocks.
template<bool PASS2>
__global__ __launch_bounds__(1024, 8) void k_spmm(const ushort* __restrict__ xin,
                                                  const ushort* __restrict__ xsub,
                                                  ushort* __restrict__ yout,
                                                  const int* __restrict__ rcnt,
                                                  const uint* __restrict__ pkv) {
  __shared__ ushort slab[4096*8];                        // 64 KiB, 16B rows
  const char* slb = (const char*)slab;
  const int t = threadIdx.x, b = blockIdx.x;
  #pragma unroll 1
  for (int task = 0; task < 2; ++task) {
    int unit, r0, nr;
    if (task == 0) { unit = ((b & 7) << 6) + (b >> 3); r0 = 0; nr = 4096; }
    else           { unit = 512 + (b >> 5); r0 = (b & 31) * 128; nr = 128; }
    const int c0 = unit * 8;
    #pragma unroll 1
    for (int s = 0; s < 2; ++s) {
      if (PASS2 || s == 0) {                             // pass1 shares the x slab
        if (task | s) __syncthreads();                   // walkers done before restage
        const ushort* src = xin + (PASS2 ? (size_t)s * MATSZ : (size_t)0) + c0;
        #pragma unroll
        for (int it = 0; it < 4; ++it) {
          const int j = it * 1024 + t;
          *(uint4*)&slab[j * 8] = *(const uint4*)&src[(size_t)j * RL];
        }
        __syncthreads();
      }
      const int sb = s << 12;
      ushort* yo = yout + (size_t)s * MATSZ + c0;
      for (int r = r0 + t; r < r0 + nr; r += 1024) {     // 1 lane per output row
        const int rb = sb + r;
        int p = rb * ELLW;
        const int pe = p + rcnt[rb];
        float a0=0.f,a1=0.f,a2=0.f,a3=0.f,a4=0.f,a5=0.f,a6=0.f,a7=0.f;
        for (; p < pe; p += 8) {                         // counts are multiples of 8
          const uint4 e0 = *(const uint4*)&pkv[p];
          const uint4 e1 = *(const uint4*)&pkv[p + 4];
          PROC4(e0);
          PROC4(e1);
        }
        uint4 o;
        if (PASS2) {
          const uint4 xv = *(const uint4*)&xsub[(size_t)r*RL + c0];
          o.x = pack2(2.f*a0 - blo(xv.x), 2.f*a1 - bhi(xv.x));
          o.y = pack2(2.f*a2 - blo(xv.y), 2.f*a3 - bhi(xv.y));
          o.z = pack2(2.f*a4 - blo(xv.z), 2.f*a5 - bhi(xv.z));
          o.w = pack2(2.f*a6 - blo(xv.w), 2.f*a7 - bhi(xv.w));
        } else {
          o.x = pack2(a0,a1); o.y = pack2(a2,a3); o.z = pack2(a4,a5); o.w = pack2(a6,a7);
        }
        *(uint4*)&yo[(size_t)r*RL] = o;
      }
    }
  }
}

// ---------------- W pre-pack into MFMA B-fragment order (bf16) ----------------
__global__ __launch_bounds__(256) void k_wpack(const float* __restrict__ W1, const float* __restrict__ W2,
                                               ushort* __restrict__ Wp1, ushort* __restrict__ Wp2) {
  const int tid = blockIdx.x*256 + threadIdx.x;
  const int i = tid & 7, l = (tid >> 3) & 63;
  if (tid < 45056) {
    const int g = tid >> 9, tt = g / 11, kk = g % 11;
    const int r = kk*32 + (l>>4)*8 + i, c = tt*16 + (l & 15);
    Wp1[tid] = (r < 330) ? (ushort)f2bf(W1[(size_t)r*128 + c]) : (ushort)0;
  } else {
    const int t2 = tid - 45056;
    const int g = t2 >> 9, tt = g / 11, kk = g % 11;
    const int r = kk*32 + (l>>4)*8 + i, c = tt*16 + (l & 15);
    Wp2[t2] = (r < 330) ? (ushort)f2bf(W2[(size_t)r*64 + c]) : (ushort)0;
  }
}

// ---------------- gconv1 output GEMM (MFMA), fused sigmoid + r*hx + u ----------------
__global__ __launch_bounds__(256) void k_gemm1(const ushort* __restrict__ x0, const ushort* __restrict__ y1,
                                               const ushort* __restrict__ y2, const ushort* __restrict__ Wp,
                                               const float* __restrict__ bias, const float* __restrict__ hx,
                                               ushort* __restrict__ x0w, ushort* __restrict__ ubuf) {
  __shared__ ushort Xs[64*XSTR];
  const int n = blockIdx.x, t = threadIdx.x;
  for (int q = t; q < 64*XSTR/4; q += 256) ((unsigned long long*)Xs)[q] = 0ull;
  __syncthreads();
  for (int m = 0; m < 5; ++m) {
    const ushort* mp;
    if (m == 0) mp = x0; else { mp = (m & 1) ? y1 : y2; if (m >= 3) mp += MATSZ; }
    mp += (size_t)n * RL;
    for (int q = t; q < RL; q += 256) {
      const int b = q / 66, f = q - b*66;
      Xs[b*XSTR + f*5 + m] = mp[q];
    }
  }
  __syncthreads();
  const int w = t >> 6, l = t & 63;
  const int b0 = w * 16;
  f32x4 acc[8];
  for (int i = 0; i < 8; ++i) acc[i] = (f32x4){0.f,0.f,0.f,0.f};
  const int arow = b0 + (l & 15), koff0 = (l >> 4) * 8;
  for (int kk = 0; kk < 11; ++kk) {
    const short8 af = *(const short8*)&Xs[arow*XSTR + kk*32 + koff0];
    #pragma unroll
    for (int tt = 0; tt < 8; ++tt) {
      const short8 bf = *(const short8*)&Wp[(((size_t)tt*11 + kk)*64 + l)*8];
      acc[tt] = __builtin_amdgcn_mfma_f32_16x16x32_bf16(af, bf, acc[tt], 0, 0, 0);
    }
  }
  const int rg = (l >> 4) * 4;
  #pragma unroll
  for (int tt = 0; tt < 8; ++tt) {
    const int o = tt*16 + (l & 15);
    const float bs = bias[o];
    #pragma unroll
    for (int r = 0; r < 4; ++r) {
      const int b = b0 + rg + r;
      const float v = acc[tt][r] + bs;
      const float sg = 1.0f / (1.0f + __expf(-v));
      if (o < Uu) {
        const float h = hx[(size_t)b*NU + (size_t)n*Uu + o];
        x0w[(size_t)n*RL + b*66 + 2 + o] = (ushort)f2bf(sg * h);
      } else {
        ubuf[(size_t)b*NU + (size_t)n*Uu + (o - Uu)] = (ushort)f2bf(sg);
      }
    }
  }
}

// ---------------- gconv2 output GEMM (MFMA), fused tanh + final gate ----------------
__global__ __launch_bounds__(256) void k_gemm2(const ushort* __restrict__ x0, const ushort* __restrict__ y1,
                                               const ushort* __restrict__ y2, const ushort* __restrict__ Wp,
                                               const float* __restrict__ bias, const float* __restrict__ hx,
                                               const ushort* __restrict__ ubuf, float* __restrict__ out) {
  __shared__ ushort Xs[64*XSTR];
  const int n = blockIdx.x, t = threadIdx.x;
  for (int q = t; q < 64*XSTR/4; q += 256) ((unsigned long long*)Xs)[q] = 0ull;
  __syncthreads();
  for (int m = 0; m < 5; ++m) {
    const ushort* mp;
    if (m == 0) mp = x0; else { mp = (m & 1) ? y1 : y2; if (m >= 3) mp += MATSZ; }
    mp += (size_t)n * RL;
    for (int q = t; q < RL; q += 256) {
      const int b = q / 66, f = q - b*66;
      Xs[b*XSTR + f*5 + m] = mp[q];
    }
  }
  __syncthreads();
  const int w = t >> 6, l = t & 63;
  const int b0 = w * 16;
  f32x4 acc[4];
  for (int i = 0; i < 4; ++i) acc[i] = (f32x4){0.f,0.f,0.f,0.f};
  const int arow = b0 + (l & 15), koff0 = (l >> 4) * 8;
  for (int kk = 0; kk < 11; ++kk) {
    const short8 af = *(const short8*)&Xs[arow*XSTR + kk*32 + koff0];
    #pragma unroll
    for (int tt = 0; tt < 4; ++tt) {
      const short8 bf = *(const short8*)&Wp[(((size_t)tt*11 + kk)*64 + l)*8];
      acc[tt] = __builtin_amdgcn_mfma_f32_16x16x32_bf16(af, bf, acc[tt], 0, 0, 0);
    }
  }
  const int rg = (l >> 4) * 4;
  #pragma unroll
  for (int tt = 0; tt < 4; ++tt) {
    const int o = tt*16 + (l & 15);
    const float bs = bias[o];
    #pragma unroll
    for (int r = 0; r < 4; ++r) {
      const int b = b0 + rg + r;
      const float c = tanhf(acc[tt][r] + bs);
      const size_t ix = (size_t)b*NU + (size_t)n*Uu + o;
      const float u = __uint_as_float(((uint)ubuf[ix]) << 16);
      const float h = hx[ix];
      out[ix] = u*h + (1.0f - u)*c;
    }
  }
}

extern "C" void kernel_launch(void* const* d_in, const int* in_sizes, int n_in,
                              void* d_out, int out_size, void* d_ws, size_t ws_size,
                              hipStream_t stream) {
  const float* inp = (const float*)d_in[0];
  const float* hx  = (const float*)d_in[1];
  const float* sup = (const float*)d_in[2];
  const float* ruW = (const float*)d_in[3];
  const float* ruB = (const float*)d_in[4];
  const float* gW  = (const float*)d_in[5];
  const float* gB  = (const float*)d_in[6];
  float* out = (float*)d_out;

  // workspace (bf16 intermediates): x0 | y1[2] | y2[2] | u | Wpk | ELL
  ushort* x0   = (ushort*)d_ws;
  ushort* y1   = x0 + MATSZ;
  ushort* y2   = y1 + 2*MATSZ;
  ushort* ubuf = y2 + 2*MATSZ;
  ushort* Wp1  = ubuf + (size_t)Bb*NU;
  ushort* Wp2  = Wp1 + 45056;
  uint* pkv  = (uint*)(Wp2 + 22528);          // 8192*112 uints, rows 16B-aligned
  int*  rcnt = (int*)(pkv + (size_t)8192*ELLW);

  k_fill<<<2048, 256, 0, stream>>>(sup, pkv, rcnt);
  k_wpack<<<264, 256, 0, stream>>>(ruW, gW, Wp1, Wp2);
  k_bx0<<<Nn, 256, 0, stream>>>(inp, hx, x0);

  // gconv1
  k_spmm<false><<<512, 1024, 0, stream>>>(x0, nullptr, y1, rcnt, pkv);
  k_spmm<true ><<<512, 1024, 0, stream>>>(y1, x0,      y2, rcnt, pkv);
  k_gemm1<<<Nn, 256, 0, stream>>>(x0, y1, y2, Wp1, ruB, hx, x0, ubuf);
  // gconv2 (x0 state slots now hold bf16(r*hx))
  k_spmm<false><<<512, 1024, 0, stream>>>(x0, nullptr, y1, rcnt, pkv);
  k_spmm<true ><<<512, 1024, 0, stream>>>(y1, x0,      y2, rcnt, pkv);
  k_gemm2<<<Nn, 256, 0, stream>>>(x0, y1, y2, Wp2, gB, hx, ubuf, out);
}